// Round 9
// baseline (68.021 us; speedup 1.0000x reference)
//
#include <hip/hip_runtime.h>
#include <math.h>

#define NHEADS 4
#define HDIM   32
#define DMODEL 128
#define SLEN   8192
#define BATCH  8
#define QKVC   384   // 3 * NHEADS * HDIM

typedef __bf16 bf16x8 __attribute__((ext_vector_type(8)));
typedef float  f32x4  __attribute__((ext_vector_type(4)));

// round-to-nearest-even f32 -> bf16 bits
static __device__ __forceinline__ unsigned short f2bf(float f) {
    union { float f; unsigned int u; } v; v.f = f;
    unsigned int r = (v.u + 0x7FFFu + ((v.u >> 16) & 1u)) >> 16;
    return (unsigned short)r;
}
// hardware cvt pack (v_cvt_pk_bf16_f32)
static __device__ __forceinline__ unsigned int pk2(float a, float b) {
    unsigned short ua = __builtin_bit_cast(unsigned short, (__bf16)a);
    unsigned short ub = __builtin_bit_cast(unsigned short, (__bf16)b);
    return (unsigned int)ua | ((unsigned int)ub << 16);
}

// ---------------------------------------------------------------------------
// Kernel P: prep. blockIdx segments:
//   [0,64) : W_out f32[8192][128] -> Wt bf16 [128][8192] (transpose+cvt)
//   [64,88): W_qkv -> MFMA A-fragment buffer wfb (bf16, fragment order)
//            wfb[((J*4+ks)*64+lane)*8+e] = bf16(Wqkv[(ks*32+(lane>>4)*8+e)*384
//                                               + J*16 + (lane&15)])
// ---------------------------------------------------------------------------
__global__ __launch_bounds__(256) void k_prep(
    const float* __restrict__ Wout, unsigned short* __restrict__ Wt,
    const float* __restrict__ Wqkv, unsigned short* __restrict__ wfb)
{
    const int tid = threadIdx.x;
    const int bx  = blockIdx.x;

    if (bx < 64) {
        __shared__ unsigned short ts[128][136];
        const float* src = Wout + (long)bx * 128 * 128;
        #pragma unroll
        for (int i = 0; i < 64; ++i) {
            const int idx = tid + i * 256;
            const int kk = idx >> 7, n = idx & 127;
            ts[n][kk] = f2bf(src[idx]);
        }
        __syncthreads();
        #pragma unroll
        for (int i = 0; i < 64; ++i) {
            const int idx = tid + i * 256;
            const int n = idx >> 7, kk = idx & 127;
            Wt[(long)n * SLEN + bx * 128 + kk] = ts[n][kk];
        }
    } else {
        const int idx  = (bx - 64) * 256 + tid;   // 0..6143
        const int lane = idx & 63;
        const int ks   = (idx >> 6) & 3;
        const int J    = idx >> 8;                // 0..23 channel tile
        const int ch   = J * 16 + (lane & 15);
        const int kb   = ks * 32 + (lane >> 4) * 8;
        unsigned short t[8];
        #pragma unroll
        for (int e = 0; e < 8; ++e) t[e] = f2bf(Wqkv[(kb + e) * QKVC + ch]);
        *(uint4*)(wfb + (long)idx * 8) = *(const uint4*)t;
    }
}

// ---------------------------------------------------------------------------
// Kernel 1: FULLY fused QKV + head-mixing attention. ZERO LDS, ZERO barriers.
// 512 blocks x 256 thr; each WAVE independently owns 32 positions (nt=2).
// Wave computes ALL 24 channel-tiles: acc[J][nt] = qkv[J*16+lhi*4+r][nt*16+l16]
// => position's 384 channels live in lanes {l16,+16,+32,+48}; softmax =
// per-lane FMA partials + shfl_xor(16)+shfl_xor(32); PV lane-local; direct
// coalesced bf16 stores. q/k/v consumed at f32 accumulator precision.
// ---------------------------------------------------------------------------
__global__ __launch_bounds__(256, 2) void k_fused(
    const float* __restrict__ x,
    const unsigned short* __restrict__ wfb,
    const float* __restrict__ bqkv,
    unsigned short* __restrict__ attn_out)   // bf16 [65536][128]
{
    const int tid  = threadIdx.x;
    const int lane = tid & 63;
    const int wave = tid >> 6;
    const int l16  = lane & 15;
    const int lhi  = lane >> 4;
    const long pw  = ((long)blockIdx.x * 4 + wave) * 32;   // wave's 32 positions

    f32x4 acc[24][2];
    #pragma unroll
    for (int j = 0; j < 24; ++j) {
        acc[j][0] = (f32x4){0.f, 0.f, 0.f, 0.f};
        acc[j][1] = (f32x4){0.f, 0.f, 0.f, 0.f};
    }

    const float* xb0 = x + (pw + l16) * DMODEL + lhi * 8;
    const float* xb1 = xb0 + 16 * DMODEL;
    const unsigned short* wl = wfb + (long)lane * 8;

    #pragma unroll
    for (int ks = 0; ks < 4; ++ks) {
        // x B-fragments for this ks (live only this iteration)
        bf16x8 xf0, xf1;
        {
            const float4 a = *(const float4*)(xb0 + ks * 32);
            const float4 b = *(const float4*)(xb0 + ks * 32 + 4);
            unsigned int t[4] = { pk2(a.x, a.y), pk2(a.z, a.w), pk2(b.x, b.y), pk2(b.z, b.w) };
            xf0 = __builtin_bit_cast(bf16x8, *(const uint4*)t);
            const float4 c = *(const float4*)(xb1 + ks * 32);
            const float4 d = *(const float4*)(xb1 + ks * 32 + 4);
            unsigned int u[4] = { pk2(c.x, c.y), pk2(c.z, c.w), pk2(d.x, d.y), pk2(d.z, d.w) };
            xf1 = __builtin_bit_cast(bf16x8, *(const uint4*)u);
        }
        #pragma unroll
        for (int j = 0; j < 24; ++j) {
            const bf16x8 wj = __builtin_bit_cast(bf16x8,
                *(const uint4*)(wl + ((j * 4 + ks) << 9)));
            acc[j][0] = __builtin_amdgcn_mfma_f32_16x16x32_bf16(wj, xf0, acc[j][0], 0, 0, 0);
            acc[j][1] = __builtin_amdgcn_mfma_f32_16x16x32_bf16(wj, xf1, acc[j][1], 0, 0, 0);
        }
    }

    // bias (zeros in this instance; kept for generality)
    #pragma unroll
    for (int j = 0; j < 24; ++j) {
        const float4 bb = *(const float4*)(bqkv + j * 16 + lhi * 4);
        #pragma unroll
        for (int nt = 0; nt < 2; ++nt) {
            acc[j][nt][0] += bb.x; acc[j][nt][1] += bb.y;
            acc[j][nt][2] += bb.z; acc[j][nt][3] += bb.w;
        }
    }

    const float scale = 0.17677669529663687f;   // 32^-0.5

    #pragma unroll
    for (int nt = 0; nt < 2; ++nt) {
        // scores: s[qh][kh], per-lane 8-d partial + butterfly over lhi lanes
        float s[4][4];
        #pragma unroll
        for (int qh = 0; qh < 4; ++qh) {
            #pragma unroll
            for (int kh = 0; kh < 4; ++kh) {
                float v = 0.f;
                #pragma unroll
                for (int jj = 0; jj < 2; ++jj)
                    #pragma unroll
                    for (int r = 0; r < 4; ++r)
                        v = fmaf(acc[qh * 6 + jj][nt][r], acc[kh * 6 + 2 + jj][nt][r], v);
                v += __shfl_xor(v, 16);
                v += __shfl_xor(v, 32);
                s[qh][kh] = v * scale;
            }
        }

        unsigned short* obase = attn_out + (pw + nt * 16 + l16) * DMODEL;
        #pragma unroll
        for (int qh = 0; qh < 4; ++qh) {
            const float m = fmaxf(fmaxf(s[qh][0], s[qh][1]), fmaxf(s[qh][2], s[qh][3]));
            const float e0 = __expf(s[qh][0] - m);
            const float e1 = __expf(s[qh][1] - m);
            const float e2 = __expf(s[qh][2] - m);
            const float e3 = __expf(s[qh][3] - m);
            const float inv = 1.f / (e0 + e1 + e2 + e3);
            const float w0 = e0 * inv, w1 = e1 * inv, w2 = e2 * inv, w3 = e3 * inv;
            #pragma unroll
            for (int jj = 0; jj < 2; ++jj) {
                float o[4];
                #pragma unroll
                for (int r = 0; r < 4; ++r)
                    o[r] = w0 * acc[4  + jj][nt][r] + w1 * acc[10 + jj][nt][r]
                         + w2 * acc[16 + jj][nt][r] + w3 * acc[22 + jj][nt][r];
                uint2 u;
                u.x = pk2(o[0], o[1]);
                u.y = pk2(o[2], o[3]);
                *(uint2*)(obase + qh * 32 + jj * 16 + lhi * 4) = u;
            }
        }
    }
}

// ---------------------------------------------------------------------------
// Kernel 2: final GEMM partials via bf16 MFMA.
//   C(1024x128) = Aflat(1024x8192 bf16) @ W(8192x128)
// ---------------------------------------------------------------------------
__global__ __launch_bounds__(256, 2) void k_fgemm_mfma(
    const unsigned short* __restrict__ attnBf,   // [1024][8192] bf16 (flat view)
    const unsigned short* __restrict__ WtBf,     // [128][8192] bf16
    float* __restrict__ P)                       // [16][1024][128] f32 partials
{
    __shared__ unsigned short As[64][136];
    __shared__ unsigned short Ws[128][136];

    const int tid   = threadIdx.x;
    const int mtile = blockIdx.x >> 4;
    const int kc    = blockIdx.x & 15;
    const int lane  = tid & 63;
    const int wave  = tid >> 6;
    const int l16   = lane & 15;
    const int lhi   = lane >> 4;

    f32x4 acc[4][2];
    #pragma unroll
    for (int mf = 0; mf < 4; ++mf)
        #pragma unroll
        for (int nt = 0; nt < 2; ++nt) acc[mf][nt] = (f32x4){0.f, 0.f, 0.f, 0.f};

    for (int st = 0; st < 4; ++st) {
        const int k0 = kc * 512 + st * 128;
        __syncthreads();
        #pragma unroll
        for (int i = 0; i < 4; ++i) {
            const int c = tid + i * 256;
            const int m = c >> 4, k8 = c & 15;
            const uint4 v = *(const uint4*)(attnBf + (long)(mtile * 64 + m) * SLEN + k0 + k8 * 8);
            *(uint4*)(&As[m][k8 * 8]) = v;
        }
        #pragma unroll
        for (int i = 0; i < 8; ++i) {
            const int c = tid + i * 256;
            const int n = c >> 4, k8 = c & 15;
            const uint4 v = *(const uint4*)(WtBf + (long)n * SLEN + k0 + k8 * 8);
            *(uint4*)(&Ws[n][k8 * 8]) = v;
        }
        __syncthreads();

        #pragma unroll
        for (int ks = 0; ks < 4; ++ks) {
            const int kk = ks * 32 + lhi * 8;
            bf16x8 af[4], bfr[2];
            #pragma unroll
            for (int mf = 0; mf < 4; ++mf)
                af[mf] = __builtin_bit_cast(bf16x8, *(const uint4*)(&As[mf * 16 + l16][kk]));
            #pragma unroll
            for (int nt = 0; nt < 2; ++nt)
                bfr[nt] = __builtin_bit_cast(bf16x8, *(const uint4*)(&Ws[(wave * 2 + nt) * 16 + l16][kk]));
            #pragma unroll
            for (int mf = 0; mf < 4; ++mf)
                #pragma unroll
                for (int nt = 0; nt < 2; ++nt)
                    acc[mf][nt] = __builtin_amdgcn_mfma_f32_16x16x32_bf16(af[mf], bfr[nt], acc[mf][nt], 0, 0, 0);
        }
    }

    float* Pp = P + ((long)kc * 1024 + mtile * 64) * 128;
    #pragma unroll
    for (int mf = 0; mf < 4; ++mf) {
        #pragma unroll
        for (int nt = 0; nt < 2; ++nt) {
            const int n = (wave * 2 + nt) * 16 + l16;
            #pragma unroll
            for (int r = 0; r < 4; ++r) {
                const int m = mf * 16 + lhi * 4 + r;
                Pp[m * 128 + n] = acc[mf][nt][r];
            }
        }
    }
}

// ---------------------------------------------------------------------------
// Kernel 3: reduce 16 K-chunk partials + bias -> out (also clears poison).
// ---------------------------------------------------------------------------
__global__ __launch_bounds__(256) void k_reduce(
    const float* __restrict__ P, const float* __restrict__ bout,
    float* __restrict__ out)
{
    const int idx = blockIdx.x * 256 + threadIdx.x;
    float v = bout[idx & 127];
    #pragma unroll
    for (int kcc = 0; kcc < 16; ++kcc) v += P[(long)kcc * 131072 + idx];
    out[idx] = v;
}

// ---------------------------------------------------------------------------
extern "C" void kernel_launch(void* const* d_in, const int* in_sizes, int n_in,
                              void* d_out, int out_size, void* d_ws, size_t ws_size,
                              hipStream_t stream)
{
    const float* x    = (const float*)d_in[0];
    const float* Wqkv = (const float*)d_in[1];
    const float* bqkv = (const float*)d_in[2];
    const float* Wout = (const float*)d_in[3];
    const float* bout = (const float*)d_in[4];
    float* out = (float*)d_out;

    // ws: [0,16M) attn bf16 | [16,18M) Wt bf16 | [18,26M) P f32 | [26M..) wfb
    unsigned short* attnBf = (unsigned short*)d_ws;
    unsigned short* WtBf   = (unsigned short*)((char*)d_ws + (16u << 20));
    float*          P      = (float*)((char*)d_ws + (18u << 20));
    unsigned short* wfb    = (unsigned short*)((char*)d_ws + (26u << 20));

    k_prep<<<88, 256, 0, stream>>>(Wout, WtBf, Wqkv, wfb);
    k_fused<<<512, 256, 0, stream>>>(x, wfb, bqkv, attnBf);
    k_fgemm_mfma<<<256, 256, 0, stream>>>(attnBf, WtBf, P);
    k_reduce<<<512, 256, 0, stream>>>(P, bout, out);
}

// Round 10
// 43.757 us; speedup vs baseline: 1.5545x; 1.5545x over previous
//
#include <hip/hip_runtime.h>
#include <math.h>

#define NHEADS 4
#define HDIM   32
#define DMODEL 128
#define SLEN   8192
#define BATCH  8
#define QKVC   384   // 3 * NHEADS * HDIM

typedef __bf16 bf16x8 __attribute__((ext_vector_type(8)));
typedef float  f32x4  __attribute__((ext_vector_type(4)));

// round-to-nearest-even f32 -> bf16 bits
static __device__ __forceinline__ unsigned short f2bf(float f) {
    union { float f; unsigned int u; } v; v.f = f;
    unsigned int r = (v.u + 0x7FFFu + ((v.u >> 16) & 1u)) >> 16;
    return (unsigned short)r;
}
// hardware cvt pack (v_cvt_pk_bf16_f32)
static __device__ __forceinline__ unsigned int pk2(float a, float b) {
    unsigned short ua = __builtin_bit_cast(unsigned short, (__bf16)a);
    unsigned short ub = __builtin_bit_cast(unsigned short, (__bf16)b);
    return (unsigned int)ua | ((unsigned int)ub << 16);
}
static __device__ __forceinline__ float bf_lo(unsigned int u) {
    union { unsigned int u; float f; } v; v.u = u << 16; return v.f;
}
static __device__ __forceinline__ float bf_hi(unsigned int u) {
    union { unsigned int u; float f; } v; v.u = u & 0xffff0000u; return v.f;
}

// ---------------------------------------------------------------------------
// Kernel P: prep. blockIdx segments:
//   [0,64) : W_out f32[8192][128] -> Wt bf16 [128][8192] (transpose+cvt)
//   [64,88): W_qkv -> MFMA A-fragment buffer wfb (bf16, fragment order)
//            wfb[((J*4+ks)*64+lane)*8+e] = bf16(Wqkv[(ks*32+(lane>>4)*8+e)*384
//                                               + J*16 + (lane&15)])
// ---------------------------------------------------------------------------
__global__ __launch_bounds__(256) void k_prep(
    const float* __restrict__ Wout, unsigned short* __restrict__ Wt,
    const float* __restrict__ Wqkv, unsigned short* __restrict__ wfb)
{
    const int tid = threadIdx.x;
    const int bx  = blockIdx.x;

    if (bx < 64) {
        __shared__ unsigned short ts[128][136];
        const float* src = Wout + (long)bx * 128 * 128;
        #pragma unroll
        for (int i = 0; i < 64; ++i) {
            const int idx = tid + i * 256;
            const int kk = idx >> 7, n = idx & 127;
            ts[n][kk] = f2bf(src[idx]);
        }
        __syncthreads();
        #pragma unroll
        for (int i = 0; i < 64; ++i) {
            const int idx = tid + i * 256;
            const int n = idx >> 7, kk = idx & 127;
            Wt[(long)n * SLEN + bx * 128 + kk] = ts[n][kk];
        }
    } else {
        const int idx  = (bx - 64) * 256 + tid;   // 0..6143
        const int lane = idx & 63;
        const int ks   = (idx >> 6) & 3;
        const int J    = idx >> 8;                // 0..23 channel tile
        const int ch   = J * 16 + (lane & 15);
        const int kb   = ks * 32 + (lane >> 4) * 8;
        unsigned short t[8];
        #pragma unroll
        for (int e = 0; e < 8; ++e) t[e] = f2bf(Wqkv[(kb + e) * QKVC + ch]);
        *(uint4*)(wfb + (long)idx * 8) = *(const uint4*)t;
    }
}

// ---------------------------------------------------------------------------
// Kernel 1: fused QKV projection + per-position head-mixing attention.
// 1024 blocks x 256 thr; TWO 32-position tiles per block, software-pipelined:
// tile-1's global x loads are issued during tile-0's MFMA phase and written
// to LDS at the end of tile-0's epilogue -> HBM latency hidden under compute.
// Per tile: MFMA qkv^T (W = A operand; lane owns 4 consecutive channels) ->
// packed bf16 b64 writes into XOR-swizzled qsm -> barrier -> full-width
// epilogue (p,qh,h) with shfl_xor(1) score completion -> coalesced store.
// ---------------------------------------------------------------------------
__global__ __launch_bounds__(256, 3) void k_qkv_attn_mfma(
    const float* __restrict__ x,
    const unsigned short* __restrict__ wfb,
    const float* __restrict__ bqkv,
    unsigned short* __restrict__ attn_out)   // bf16 [65536][128]
{
    __shared__ unsigned short xs[32 * 136];   // x tile bf16
    __shared__ unsigned short qsm[32 * 384];  // qkv bf16, chunk-swizzled rows

    const int tid  = threadIdx.x;
    const int lane = tid & 63;
    const int wave = tid >> 6;
    const int l16  = lane & 15;
    const int lhi  = lane >> 4;
    const long p00 = (long)blockIdx.x * 64;
    const int spos = tid >> 3;   // 0..31
    const int sseg = tid & 7;    // 0..7

    // stage a 32-pos tile from 4 float4 regs into xs (cvt + 2 b128 writes)
    auto stage_write = [&](float4 a0, float4 a1, float4 a2, float4 a3) {
        unsigned int t[8] = {
            pk2(a0.x, a0.y), pk2(a0.z, a0.w), pk2(a1.x, a1.y), pk2(a1.z, a1.w),
            pk2(a2.x, a2.y), pk2(a2.z, a2.w), pk2(a3.x, a3.y), pk2(a3.z, a3.w) };
        *(uint4*)(xs + spos * 136 + sseg * 16)     = ((const uint4*)t)[0];
        *(uint4*)(xs + spos * 136 + sseg * 16 + 8) = ((const uint4*)t)[1];
    };

    // MFMA phase: reads xs + wfb, writes qsm (+bias), bf16 packed b64 stores
    auto mfma_phase = [&]() {
        f32x4 acc[6][2];
        #pragma unroll
        for (int j = 0; j < 6; ++j)
            #pragma unroll
            for (int nt = 0; nt < 2; ++nt) acc[j][nt] = (f32x4){0.f, 0.f, 0.f, 0.f};

        const unsigned short* wbase = wfb + ((long)(wave * 24) * 64 + lane) * 8;
        #pragma unroll
        for (int ks = 0; ks < 4; ++ks) {
            const bf16x8 xf0 = __builtin_bit_cast(bf16x8,
                *(const uint4*)(xs + l16 * 136 + ks * 32 + lhi * 8));
            const bf16x8 xf1 = __builtin_bit_cast(bf16x8,
                *(const uint4*)(xs + (16 + l16) * 136 + ks * 32 + lhi * 8));
            #pragma unroll
            for (int j = 0; j < 6; ++j) {
                const bf16x8 wj = __builtin_bit_cast(bf16x8,
                    *(const uint4*)(wbase + (j * 4 + ks) * 512));
                acc[j][0] = __builtin_amdgcn_mfma_f32_16x16x32_bf16(wj, xf0, acc[j][0], 0, 0, 0);
                acc[j][1] = __builtin_amdgcn_mfma_f32_16x16x32_bf16(wj, xf1, acc[j][1], 0, 0, 0);
            }
        }
        #pragma unroll
        for (int j = 0; j < 6; ++j) {
            const float4 bb = *(const float4*)(bqkv + wave * 96 + j * 16 + lhi * 4);
            const int c     = wave * 96 + lhi * 4 + j * 16;
            const int chunk = c >> 3;
            const int sub   = c & 7;          // 0 or 4
            #pragma unroll
            for (int nt = 0; nt < 2; ++nt) {
                const int p = nt * 16 + l16;  // p & 15 == l16
                uint2 u;
                u.x = pk2(acc[j][nt][0] + bb.x, acc[j][nt][1] + bb.y);
                u.y = pk2(acc[j][nt][2] + bb.z, acc[j][nt][3] + bb.w);
                *(uint2*)(qsm + p * 384 + (((chunk ^ l16) << 3) + sub)) = u;
            }
        }
    };

    // epilogue: 256 threads = (p = tid>>3, qh = (tid>>1)&3, h = tid&1)
    auto epilogue = [&](long p0) {
        const int p   = tid >> 3;
        const int qh  = (tid >> 1) & 3;
        const int h   = tid & 1;
        const int psw = p & 15;
        const unsigned short* row = qsm + p * 384;
        const float scale = 0.17677669529663687f;   // 32^-0.5

        float qf[16];
        {
            const int qc = qh * 12 + h * 2;
            #pragma unroll
            for (int cc = 0; cc < 2; ++cc) {
                const uint4 qv = *(const uint4*)(row + (((qc + cc) ^ psw) << 3));
                const unsigned int* w = (const unsigned int*)&qv;
                #pragma unroll
                for (int k = 0; k < 4; ++k) {
                    qf[cc * 8 + 2 * k]     = bf_lo(w[k]);
                    qf[cc * 8 + 2 * k + 1] = bf_hi(w[k]);
                }
            }
        }
        float sc[NHEADS];
        #pragma unroll
        for (int kh = 0; kh < NHEADS; ++kh) {
            float s = 0.f;
            const int kc = kh * 12 + 4 + h * 2;
            #pragma unroll
            for (int cc = 0; cc < 2; ++cc) {
                const uint4 kv = *(const uint4*)(row + (((kc + cc) ^ psw) << 3));
                const unsigned int* w = (const unsigned int*)&kv;
                #pragma unroll
                for (int k = 0; k < 4; ++k) {
                    s = fmaf(bf_lo(w[k]), qf[cc * 8 + 2 * k], s);
                    s = fmaf(bf_hi(w[k]), qf[cc * 8 + 2 * k + 1], s);
                }
            }
            sc[kh] = (s + __shfl_xor(s, 1)) * scale;
        }
        const float m = fmaxf(fmaxf(sc[0], sc[1]), fmaxf(sc[2], sc[3]));
        float ew[NHEADS], sum = 0.f;
        #pragma unroll
        for (int kh = 0; kh < NHEADS; ++kh) { ew[kh] = __expf(sc[kh] - m); sum += ew[kh]; }
        const float inv = 1.f / sum;
        #pragma unroll
        for (int kh = 0; kh < NHEADS; ++kh) ew[kh] *= inv;

        float o[16];
        #pragma unroll
        for (int e = 0; e < 16; ++e) o[e] = 0.f;
        #pragma unroll
        for (int kh = 0; kh < NHEADS; ++kh) {
            const float wk = ew[kh];
            const int vc = kh * 12 + 8 + h * 2;
            #pragma unroll
            for (int cc = 0; cc < 2; ++cc) {
                const uint4 vv = *(const uint4*)(row + (((vc + cc) ^ psw) << 3));
                const unsigned int* w = (const unsigned int*)&vv;
                #pragma unroll
                for (int k = 0; k < 4; ++k) {
                    o[cc * 8 + 2 * k]     = fmaf(wk, bf_lo(w[k]), o[cc * 8 + 2 * k]);
                    o[cc * 8 + 2 * k + 1] = fmaf(wk, bf_hi(w[k]), o[cc * 8 + 2 * k + 1]);
                }
            }
        }
        unsigned int ow[8];
        #pragma unroll
        for (int e = 0; e < 8; ++e) ow[e] = pk2(o[2 * e], o[2 * e + 1]);
        unsigned short* dst = attn_out + (p0 + p) * DMODEL + qh * 32 + h * 16;
        *(uint4*)(dst)     = ((const uint4*)ow)[0];
        *(uint4*)(dst + 8) = ((const uint4*)ow)[1];
    };

    // ---- prologue: stage tile 0 ----
    {
        const float* src = x + (p00 + spos) * DMODEL + sseg * 16;
        stage_write(*(const float4*)(src),     *(const float4*)(src + 4),
                    *(const float4*)(src + 8), *(const float4*)(src + 12));
    }
    __syncthreads();                 // xs(t0) ready

    // ---- tile 0: MFMA + prefetch tile 1 ----
    mfma_phase();
    float4 xv0, xv1, xv2, xv3;       // tile-1 prefetch (16 VGPR, held thru epi)
    {
        const float* src = x + (p00 + 32 + spos) * DMODEL + sseg * 16;
        xv0 = *(const float4*)(src);      xv1 = *(const float4*)(src + 4);
        xv2 = *(const float4*)(src + 8);  xv3 = *(const float4*)(src + 12);
    }
    __syncthreads();                 // qsm(t0) ready; xs(t0) consumed

    epilogue(p00);
    stage_write(xv0, xv1, xv2, xv3); // xs := tile 1 (loads arrived during epi)
    __syncthreads();                 // xs(t1) ready; qsm free

    // ---- tile 1 ----
    mfma_phase();
    __syncthreads();                 // qsm(t1) ready
    epilogue(p00 + 32);
}

// ---------------------------------------------------------------------------
// Kernel 2: final GEMM partials via bf16 MFMA.
//   C(1024x128) = Aflat(1024x8192 bf16) @ W(8192x128)
// ---------------------------------------------------------------------------
__global__ __launch_bounds__(256, 2) void k_fgemm_mfma(
    const unsigned short* __restrict__ attnBf,   // [1024][8192] bf16 (flat view)
    const unsigned short* __restrict__ WtBf,     // [128][8192] bf16
    float* __restrict__ P)                       // [16][1024][128] f32 partials
{
    __shared__ unsigned short As[64][136];
    __shared__ unsigned short Ws[128][136];

    const int tid   = threadIdx.x;
    const int mtile = blockIdx.x >> 4;
    const int kc    = blockIdx.x & 15;
    const int lane  = tid & 63;
    const int wave  = tid >> 6;
    const int l16   = lane & 15;
    const int lhi   = lane >> 4;

    f32x4 acc[4][2];
    #pragma unroll
    for (int mf = 0; mf < 4; ++mf)
        #pragma unroll
        for (int nt = 0; nt < 2; ++nt) acc[mf][nt] = (f32x4){0.f, 0.f, 0.f, 0.f};

    for (int st = 0; st < 4; ++st) {
        const int k0 = kc * 512 + st * 128;
        __syncthreads();
        #pragma unroll
        for (int i = 0; i < 4; ++i) {
            const int c = tid + i * 256;
            const int m = c >> 4, k8 = c & 15;
            const uint4 v = *(const uint4*)(attnBf + (long)(mtile * 64 + m) * SLEN + k0 + k8 * 8);
            *(uint4*)(&As[m][k8 * 8]) = v;
        }
        #pragma unroll
        for (int i = 0; i < 8; ++i) {
            const int c = tid + i * 256;
            const int n = c >> 4, k8 = c & 15;
            const uint4 v = *(const uint4*)(WtBf + (long)n * SLEN + k0 + k8 * 8);
            *(uint4*)(&Ws[n][k8 * 8]) = v;
        }
        __syncthreads();

        #pragma unroll
        for (int ks = 0; ks < 4; ++ks) {
            const int kk = ks * 32 + lhi * 8;
            bf16x8 af[4], bfr[2];
            #pragma unroll
            for (int mf = 0; mf < 4; ++mf)
                af[mf] = __builtin_bit_cast(bf16x8, *(const uint4*)(&As[mf * 16 + l16][kk]));
            #pragma unroll
            for (int nt = 0; nt < 2; ++nt)
                bfr[nt] = __builtin_bit_cast(bf16x8, *(const uint4*)(&Ws[(wave * 2 + nt) * 16 + l16][kk]));
            #pragma unroll
            for (int mf = 0; mf < 4; ++mf)
                #pragma unroll
                for (int nt = 0; nt < 2; ++nt)
                    acc[mf][nt] = __builtin_amdgcn_mfma_f32_16x16x32_bf16(af[mf], bfr[nt], acc[mf][nt], 0, 0, 0);
        }
    }

    float* Pp = P + ((long)kc * 1024 + mtile * 64) * 128;
    #pragma unroll
    for (int mf = 0; mf < 4; ++mf) {
        #pragma unroll
        for (int nt = 0; nt < 2; ++nt) {
            const int n = (wave * 2 + nt) * 16 + l16;
            #pragma unroll
            for (int r = 0; r < 4; ++r) {
                const int m = mf * 16 + lhi * 4 + r;
                Pp[m * 128 + n] = acc[mf][nt][r];
            }
        }
    }
}

// ---------------------------------------------------------------------------
// Kernel 3: reduce 16 K-chunk partials + bias -> out (also clears poison).
// ---------------------------------------------------------------------------
__global__ __launch_bounds__(256) void k_reduce(
    const float* __restrict__ P, const float* __restrict__ bout,
    float* __restrict__ out)
{
    const int idx = blockIdx.x * 256 + threadIdx.x;
    float v = bout[idx & 127];
    #pragma unroll
    for (int kcc = 0; kcc < 16; ++kcc) v += P[(long)kcc * 131072 + idx];
    out[idx] = v;
}

// ---------------------------------------------------------------------------
extern "C" void kernel_launch(void* const* d_in, const int* in_sizes, int n_in,
                              void* d_out, int out_size, void* d_ws, size_t ws_size,
                              hipStream_t stream)
{
    const float* x    = (const float*)d_in[0];
    const float* Wqkv = (const float*)d_in[1];
    const float* bqkv = (const float*)d_in[2];
    const float* Wout = (const float*)d_in[3];
    const float* bout = (const float*)d_in[4];
    float* out = (float*)d_out;

    // ws: [0,16M) attn bf16 | [16,18M) Wt bf16 | [18,26M) P f32 | [26M..) wfb
    unsigned short* attnBf = (unsigned short*)d_ws;
    unsigned short* WtBf   = (unsigned short*)((char*)d_ws + (16u << 20));
    float*          P      = (float*)((char*)d_ws + (18u << 20));
    unsigned short* wfb    = (unsigned short*)((char*)d_ws + (26u << 20));

    k_prep<<<88, 256, 0, stream>>>(Wout, WtBf, Wqkv, wfb);
    k_qkv_attn_mfma<<<1024, 256, 0, stream>>>(x, wfb, bqkv, attnBf);
    k_fgemm_mfma<<<256, 256, 0, stream>>>(attnBf, WtBf, P);
    k_reduce<<<512, 256, 0, stream>>>(P, bout, out);
}

// Round 11
// 40.054 us; speedup vs baseline: 1.6982x; 1.0924x over previous
//
#include <hip/hip_runtime.h>
#include <math.h>

#define NHEADS 4
#define HDIM   32
#define DMODEL 128
#define SLEN   8192
#define BATCH  8
#define QKVC   384   // 3 * NHEADS * HDIM

typedef __bf16 bf16x8 __attribute__((ext_vector_type(8)));
typedef float  f32x4  __attribute__((ext_vector_type(4)));

// round-to-nearest-even f32 -> bf16 bits
static __device__ __forceinline__ unsigned short f2bf(float f) {
    union { float f; unsigned int u; } v; v.f = f;
    unsigned int r = (v.u + 0x7FFFu + ((v.u >> 16) & 1u)) >> 16;
    return (unsigned short)r;
}
// hardware cvt pack (v_cvt_pk_bf16_f32)
static __device__ __forceinline__ unsigned int pk2(float a, float b) {
    unsigned short ua = __builtin_bit_cast(unsigned short, (__bf16)a);
    unsigned short ub = __builtin_bit_cast(unsigned short, (__bf16)b);
    return (unsigned int)ua | ((unsigned int)ub << 16);
}
static __device__ __forceinline__ float bf_lo(unsigned int u) {
    union { unsigned int u; float f; } v; v.u = u << 16; return v.f;
}
static __device__ __forceinline__ float bf_hi(unsigned int u) {
    union { unsigned int u; float f; } v; v.u = u & 0xffff0000u; return v.f;
}

// ---------------------------------------------------------------------------
// Kernel P: prep. blockIdx segments:
//   [0,64) : W_out f32[8192][128] -> Wt bf16 [128][8192] (transpose+cvt)
//   [64,88): W_qkv -> MFMA A-fragment buffer wfb (bf16, fragment order)
// ---------------------------------------------------------------------------
__global__ __launch_bounds__(256) void k_prep(
    const float* __restrict__ Wout, unsigned short* __restrict__ Wt,
    const float* __restrict__ Wqkv, unsigned short* __restrict__ wfb)
{
    const int tid = threadIdx.x;
    const int bx  = blockIdx.x;

    if (bx < 64) {
        __shared__ unsigned short ts[128][136];
        const float* src = Wout + (long)bx * 128 * 128;
        #pragma unroll
        for (int i = 0; i < 64; ++i) {
            const int idx = tid + i * 256;
            const int kk = idx >> 7, n = idx & 127;
            ts[n][kk] = f2bf(src[idx]);
        }
        __syncthreads();
        #pragma unroll
        for (int i = 0; i < 64; ++i) {
            const int idx = tid + i * 256;
            const int n = idx >> 7, kk = idx & 127;
            Wt[(long)n * SLEN + bx * 128 + kk] = ts[n][kk];
        }
    } else {
        const int idx  = (bx - 64) * 256 + tid;   // 0..6143
        const int lane = idx & 63;
        const int ks   = (idx >> 6) & 3;
        const int J    = idx >> 8;                // 0..23 channel tile
        const int ch   = J * 16 + (lane & 15);
        const int kb   = ks * 32 + (lane >> 4) * 8;
        unsigned short t[8];
        #pragma unroll
        for (int e = 0; e < 8; ++e) t[e] = f2bf(Wqkv[(kb + e) * QKVC + ch]);
        *(uint4*)(wfb + (long)idx * 8) = *(const uint4*)t;
    }
}

// ---------------------------------------------------------------------------
// Kernel 1: fused QKV projection + per-position head-mixing attention.
// 1024 blocks x 256 thr; TWO 32-position tiles per block, software-pipelined.
// W fragments for the wave's 6 channel-tiles are loaded ONCE per block into
// registers (24 batched uint4 loads, one latency wait) and reused across
// both tiles' MFMA phases -- eliminates the per-tile L2-latency serialization
// that dominated R6/R10 (24 dependent loads x ~250cyc inside the j,ks loop).
// ---------------------------------------------------------------------------
__global__ __launch_bounds__(256, 2) void k_qkv_attn_mfma(
    const float* __restrict__ x,
    const unsigned short* __restrict__ wfb,
    const float* __restrict__ bqkv,
    unsigned short* __restrict__ attn_out)   // bf16 [65536][128]
{
    __shared__ unsigned short xs[32 * 136];   // x tile bf16
    __shared__ unsigned short qsm[32 * 384];  // qkv bf16, chunk-swizzled rows

    const int tid  = threadIdx.x;
    const int lane = tid & 63;
    const int wave = tid >> 6;
    const int l16  = lane & 15;
    const int lhi  = lane >> 4;
    const long p00 = (long)blockIdx.x * 64;
    const int spos = tid >> 3;   // 0..31
    const int sseg = tid & 7;    // 0..7

    // ---- resident W fragments: 24 independent uint4 loads, batch-issued ----
    bf16x8 wf[6][4];
    {
        const unsigned short* wbase = wfb + ((long)(wave * 24) * 64 + lane) * 8;
        #pragma unroll
        for (int j = 0; j < 6; ++j)
            #pragma unroll
            for (int ks = 0; ks < 4; ++ks)
                wf[j][ks] = __builtin_bit_cast(bf16x8,
                    *(const uint4*)(wbase + (j * 4 + ks) * 512));
    }

    // stage a 32-pos tile from 4 float4 regs into xs (cvt + 2 b128 writes)
    auto stage_write = [&](float4 a0, float4 a1, float4 a2, float4 a3) {
        unsigned int t[8] = {
            pk2(a0.x, a0.y), pk2(a0.z, a0.w), pk2(a1.x, a1.y), pk2(a1.z, a1.w),
            pk2(a2.x, a2.y), pk2(a2.z, a2.w), pk2(a3.x, a3.y), pk2(a3.z, a3.w) };
        *(uint4*)(xs + spos * 136 + sseg * 16)     = ((const uint4*)t)[0];
        *(uint4*)(xs + spos * 136 + sseg * 16 + 8) = ((const uint4*)t)[1];
    };

    // MFMA phase: reads xs + resident wf, writes qsm (+bias)
    auto mfma_phase = [&]() {
        f32x4 acc[6][2];
        #pragma unroll
        for (int j = 0; j < 6; ++j)
            #pragma unroll
            for (int nt = 0; nt < 2; ++nt) acc[j][nt] = (f32x4){0.f, 0.f, 0.f, 0.f};

        #pragma unroll
        for (int ks = 0; ks < 4; ++ks) {
            const bf16x8 xf0 = __builtin_bit_cast(bf16x8,
                *(const uint4*)(xs + l16 * 136 + ks * 32 + lhi * 8));
            const bf16x8 xf1 = __builtin_bit_cast(bf16x8,
                *(const uint4*)(xs + (16 + l16) * 136 + ks * 32 + lhi * 8));
            #pragma unroll
            for (int j = 0; j < 6; ++j) {
                acc[j][0] = __builtin_amdgcn_mfma_f32_16x16x32_bf16(wf[j][ks], xf0, acc[j][0], 0, 0, 0);
                acc[j][1] = __builtin_amdgcn_mfma_f32_16x16x32_bf16(wf[j][ks], xf1, acc[j][1], 0, 0, 0);
            }
        }
        #pragma unroll
        for (int j = 0; j < 6; ++j) {
            const float4 bb = *(const float4*)(bqkv + wave * 96 + j * 16 + lhi * 4);
            const int c     = wave * 96 + lhi * 4 + j * 16;
            const int chunk = c >> 3;
            const int sub   = c & 7;          // 0 or 4
            #pragma unroll
            for (int nt = 0; nt < 2; ++nt) {
                const int p = nt * 16 + l16;  // p & 15 == l16
                uint2 u;
                u.x = pk2(acc[j][nt][0] + bb.x, acc[j][nt][1] + bb.y);
                u.y = pk2(acc[j][nt][2] + bb.z, acc[j][nt][3] + bb.w);
                *(uint2*)(qsm + p * 384 + (((chunk ^ l16) << 3) + sub)) = u;
            }
        }
    };

    // epilogue: 256 threads = (p = tid>>3, qh = (tid>>1)&3, h = tid&1)
    auto epilogue = [&](long p0) {
        const int p   = tid >> 3;
        const int qh  = (tid >> 1) & 3;
        const int h   = tid & 1;
        const int psw = p & 15;
        const unsigned short* row = qsm + p * 384;
        const float scale = 0.17677669529663687f;   // 32^-0.5

        float qf[16];
        {
            const int qc = qh * 12 + h * 2;
            #pragma unroll
            for (int cc = 0; cc < 2; ++cc) {
                const uint4 qv = *(const uint4*)(row + (((qc + cc) ^ psw) << 3));
                const unsigned int* w = (const unsigned int*)&qv;
                #pragma unroll
                for (int k = 0; k < 4; ++k) {
                    qf[cc * 8 + 2 * k]     = bf_lo(w[k]);
                    qf[cc * 8 + 2 * k + 1] = bf_hi(w[k]);
                }
            }
        }
        float sc[NHEADS];
        #pragma unroll
        for (int kh = 0; kh < NHEADS; ++kh) {
            float s = 0.f;
            const int kc = kh * 12 + 4 + h * 2;
            #pragma unroll
            for (int cc = 0; cc < 2; ++cc) {
                const uint4 kv = *(const uint4*)(row + (((kc + cc) ^ psw) << 3));
                const unsigned int* w = (const unsigned int*)&kv;
                #pragma unroll
                for (int k = 0; k < 4; ++k) {
                    s = fmaf(bf_lo(w[k]), qf[cc * 8 + 2 * k], s);
                    s = fmaf(bf_hi(w[k]), qf[cc * 8 + 2 * k + 1], s);
                }
            }
            sc[kh] = (s + __shfl_xor(s, 1)) * scale;
        }
        const float m = fmaxf(fmaxf(sc[0], sc[1]), fmaxf(sc[2], sc[3]));
        float ew[NHEADS], sum = 0.f;
        #pragma unroll
        for (int kh = 0; kh < NHEADS; ++kh) { ew[kh] = __expf(sc[kh] - m); sum += ew[kh]; }
        const float inv = 1.f / sum;
        #pragma unroll
        for (int kh = 0; kh < NHEADS; ++kh) ew[kh] *= inv;

        float o[16];
        #pragma unroll
        for (int e = 0; e < 16; ++e) o[e] = 0.f;
        #pragma unroll
        for (int kh = 0; kh < NHEADS; ++kh) {
            const float wk = ew[kh];
            const int vc = kh * 12 + 8 + h * 2;
            #pragma unroll
            for (int cc = 0; cc < 2; ++cc) {
                const uint4 vv = *(const uint4*)(row + (((vc + cc) ^ psw) << 3));
                const unsigned int* w = (const unsigned int*)&vv;
                #pragma unroll
                for (int k = 0; k < 4; ++k) {
                    o[cc * 8 + 2 * k]     = fmaf(wk, bf_lo(w[k]), o[cc * 8 + 2 * k]);
                    o[cc * 8 + 2 * k + 1] = fmaf(wk, bf_hi(w[k]), o[cc * 8 + 2 * k + 1]);
                }
            }
        }
        unsigned int ow[8];
        #pragma unroll
        for (int e = 0; e < 8; ++e) ow[e] = pk2(o[2 * e], o[2 * e + 1]);
        unsigned short* dst = attn_out + (p0 + p) * DMODEL + qh * 32 + h * 16;
        *(uint4*)(dst)     = ((const uint4*)ow)[0];
        *(uint4*)(dst + 8) = ((const uint4*)ow)[1];
    };

    // ---- prologue: stage tile 0 ----
    {
        const float* src = x + (p00 + spos) * DMODEL + sseg * 16;
        stage_write(*(const float4*)(src),     *(const float4*)(src + 4),
                    *(const float4*)(src + 8), *(const float4*)(src + 12));
    }
    __syncthreads();                 // xs(t0) ready

    // ---- tile 0: MFMA + prefetch tile 1 ----
    mfma_phase();
    float4 xv0, xv1, xv2, xv3;       // tile-1 prefetch (16 VGPR, held thru epi)
    {
        const float* src = x + (p00 + 32 + spos) * DMODEL + sseg * 16;
        xv0 = *(const float4*)(src);      xv1 = *(const float4*)(src + 4);
        xv2 = *(const float4*)(src + 8);  xv3 = *(const float4*)(src + 12);
    }
    __syncthreads();                 // qsm(t0) ready; xs(t0) consumed

    epilogue(p00);
    stage_write(xv0, xv1, xv2, xv3); // xs := tile 1 (loads arrived during epi)
    __syncthreads();                 // xs(t1) ready; qsm free

    // ---- tile 1 ----
    mfma_phase();
    __syncthreads();                 // qsm(t1) ready
    epilogue(p00 + 32);
}

// ---------------------------------------------------------------------------
// Kernel 2: final GEMM partials via bf16 MFMA.
//   C(1024x128) = Aflat(1024x8192 bf16) @ W(8192x128)
// ---------------------------------------------------------------------------
__global__ __launch_bounds__(256, 2) void k_fgemm_mfma(
    const unsigned short* __restrict__ attnBf,   // [1024][8192] bf16 (flat view)
    const unsigned short* __restrict__ WtBf,     // [128][8192] bf16
    float* __restrict__ P)                       // [16][1024][128] f32 partials
{
    __shared__ unsigned short As[64][136];
    __shared__ unsigned short Ws[128][136];

    const int tid   = threadIdx.x;
    const int mtile = blockIdx.x >> 4;
    const int kc    = blockIdx.x & 15;
    const int lane  = tid & 63;
    const int wave  = tid >> 6;
    const int l16   = lane & 15;
    const int lhi   = lane >> 4;

    f32x4 acc[4][2];
    #pragma unroll
    for (int mf = 0; mf < 4; ++mf)
        #pragma unroll
        for (int nt = 0; nt < 2; ++nt) acc[mf][nt] = (f32x4){0.f, 0.f, 0.f, 0.f};

    for (int st = 0; st < 4; ++st) {
        const int k0 = kc * 512 + st * 128;
        __syncthreads();
        #pragma unroll
        for (int i = 0; i < 4; ++i) {
            const int c = tid + i * 256;
            const int m = c >> 4, k8 = c & 15;
            const uint4 v = *(const uint4*)(attnBf + (long)(mtile * 64 + m) * SLEN + k0 + k8 * 8);
            *(uint4*)(&As[m][k8 * 8]) = v;
        }
        #pragma unroll
        for (int i = 0; i < 8; ++i) {
            const int c = tid + i * 256;
            const int n = c >> 4, k8 = c & 15;
            const uint4 v = *(const uint4*)(WtBf + (long)n * SLEN + k0 + k8 * 8);
            *(uint4*)(&Ws[n][k8 * 8]) = v;
        }
        __syncthreads();

        #pragma unroll
        for (int ks = 0; ks < 4; ++ks) {
            const int kk = ks * 32 + lhi * 8;
            bf16x8 af[4], bfr[2];
            #pragma unroll
            for (int mf = 0; mf < 4; ++mf)
                af[mf] = __builtin_bit_cast(bf16x8, *(const uint4*)(&As[mf * 16 + l16][kk]));
            #pragma unroll
            for (int nt = 0; nt < 2; ++nt)
                bfr[nt] = __builtin_bit_cast(bf16x8, *(const uint4*)(&Ws[(wave * 2 + nt) * 16 + l16][kk]));
            #pragma unroll
            for (int mf = 0; mf < 4; ++mf)
                #pragma unroll
                for (int nt = 0; nt < 2; ++nt)
                    acc[mf][nt] = __builtin_amdgcn_mfma_f32_16x16x32_bf16(af[mf], bfr[nt], acc[mf][nt], 0, 0, 0);
        }
    }

    float* Pp = P + ((long)kc * 1024 + mtile * 64) * 128;
    #pragma unroll
    for (int mf = 0; mf < 4; ++mf) {
        #pragma unroll
        for (int nt = 0; nt < 2; ++nt) {
            const int n = (wave * 2 + nt) * 16 + l16;
            #pragma unroll
            for (int r = 0; r < 4; ++r) {
                const int m = mf * 16 + lhi * 4 + r;
                Pp[m * 128 + n] = acc[mf][nt][r];
            }
        }
    }
}

// ---------------------------------------------------------------------------
// Kernel 3: reduce 16 K-chunk partials + bias -> out (also clears poison).
// ---------------------------------------------------------------------------
__global__ __launch_bounds__(256) void k_reduce(
    const float* __restrict__ P, const float* __restrict__ bout,
    float* __restrict__ out)
{
    const int idx = blockIdx.x * 256 + threadIdx.x;
    float v = bout[idx & 127];
    #pragma unroll
    for (int kcc = 0; kcc < 16; ++kcc) v += P[(long)kcc * 131072 + idx];
    out[idx] = v;
}

// ---------------------------------------------------------------------------
extern "C" void kernel_launch(void* const* d_in, const int* in_sizes, int n_in,
                              void* d_out, int out_size, void* d_ws, size_t ws_size,
                              hipStream_t stream)
{
    const float* x    = (const float*)d_in[0];
    const float* Wqkv = (const float*)d_in[1];
    const float* bqkv = (const float*)d_in[2];
    const float* Wout = (const float*)d_in[3];
    const float* bout = (const float*)d_in[4];
    float* out = (float*)d_out;

    // ws: [0,16M) attn bf16 | [16,18M) Wt bf16 | [18,26M) P f32 | [26M..) wfb
    unsigned short* attnBf = (unsigned short*)d_ws;
    unsigned short* WtBf   = (unsigned short*)((char*)d_ws + (16u << 20));
    float*          P      = (float*)((char*)d_ws + (18u << 20));
    unsigned short* wfb    = (unsigned short*)((char*)d_ws + (26u << 20));

    k_prep<<<88, 256, 0, stream>>>(Wout, WtBf, Wqkv, wfb);
    k_qkv_attn_mfma<<<1024, 256, 0, stream>>>(x, wfb, bqkv, attnBf);
    k_fgemm_mfma<<<256, 256, 0, stream>>>(attnBf, WtBf, P);
    k_reduce<<<512, 256, 0, stream>>>(P, bout, out);
}

// Round 12
// 38.859 us; speedup vs baseline: 1.7504x; 1.0307x over previous
//
#include <hip/hip_runtime.h>
#include <math.h>

#define NHEADS 4
#define HDIM   32
#define DMODEL 128
#define SLEN   8192
#define BATCH  8
#define QKVC   384   // 3 * NHEADS * HDIM

typedef __bf16 bf16x8 __attribute__((ext_vector_type(8)));
typedef float  f32x4  __attribute__((ext_vector_type(4)));

// round-to-nearest-even f32 -> bf16 bits
static __device__ __forceinline__ unsigned short f2bf(float f) {
    union { float f; unsigned int u; } v; v.f = f;
    unsigned int r = (v.u + 0x7FFFu + ((v.u >> 16) & 1u)) >> 16;
    return (unsigned short)r;
}
// hardware cvt pack (v_cvt_pk_bf16_f32)
static __device__ __forceinline__ unsigned int pk2(float a, float b) {
    unsigned short ua = __builtin_bit_cast(unsigned short, (__bf16)a);
    unsigned short ub = __builtin_bit_cast(unsigned short, (__bf16)b);
    return (unsigned int)ua | ((unsigned int)ub << 16);
}
static __device__ __forceinline__ float bf_lo(unsigned int u) {
    union { unsigned int u; float f; } v; v.u = u << 16; return v.f;
}
static __device__ __forceinline__ float bf_hi(unsigned int u) {
    union { unsigned int u; float f; } v; v.u = u & 0xffff0000u; return v.f;
}

// ---------------------------------------------------------------------------
// Kernel P: prep. blockIdx segments:
//   [0,64) : W_out f32[8192][128] -> Wt bf16 [128][8192] (transpose+cvt)
//   [64,88): W_qkv -> MFMA A-fragment buffer wfb (bf16, fragment order)
// ---------------------------------------------------------------------------
__global__ __launch_bounds__(256) void k_prep(
    const float* __restrict__ Wout, unsigned short* __restrict__ Wt,
    const float* __restrict__ Wqkv, unsigned short* __restrict__ wfb)
{
    const int tid = threadIdx.x;
    const int bx  = blockIdx.x;

    if (bx < 64) {
        __shared__ unsigned short ts[128][136];
        const float* src = Wout + (long)bx * 128 * 128;
        #pragma unroll
        for (int i = 0; i < 64; ++i) {
            const int idx = tid + i * 256;
            const int kk = idx >> 7, n = idx & 127;
            ts[n][kk] = f2bf(src[idx]);
        }
        __syncthreads();
        #pragma unroll
        for (int i = 0; i < 64; ++i) {
            const int idx = tid + i * 256;
            const int n = idx >> 7, kk = idx & 127;
            Wt[(long)n * SLEN + bx * 128 + kk] = ts[n][kk];
        }
    } else {
        const int idx  = (bx - 64) * 256 + tid;   // 0..6143
        const int lane = idx & 63;
        const int ks   = (idx >> 6) & 3;
        const int J    = idx >> 8;                // 0..23 channel tile
        const int ch   = J * 16 + (lane & 15);
        const int kb   = ks * 32 + (lane >> 4) * 8;
        unsigned short t[8];
        #pragma unroll
        for (int e = 0; e < 8; ++e) t[e] = f2bf(Wqkv[(kb + e) * QKVC + ch]);
        *(uint4*)(wfb + (long)idx * 8) = *(const uint4*)t;
    }
}

// ---------------------------------------------------------------------------
// Kernel 1: fused QKV projection + per-position head-mixing attention.
// 512 blocks x 256 thr; FOUR 32-position tiles per block, software-pipelined:
// resident W fragments (loaded once, reused 4x), tile i+1's global loads
// issued during tile i's MFMA phase, written to LDS after tile i's epilogue.
// Per tile: MFMA qkv^T -> XOR-swizzled qsm -> barrier -> full-width epilogue
// (p,qh,h) with shfl_xor(1) -> coalesced store.
// ---------------------------------------------------------------------------
__global__ __launch_bounds__(256, 2) void k_qkv_attn_mfma(
    const float* __restrict__ x,
    const unsigned short* __restrict__ wfb,
    const float* __restrict__ bqkv,
    unsigned short* __restrict__ attn_out)   // bf16 [65536][128]
{
    __shared__ unsigned short xs[32 * 136];   // x tile bf16
    __shared__ unsigned short qsm[32 * 384];  // qkv bf16, chunk-swizzled rows

    const int tid  = threadIdx.x;
    const int lane = tid & 63;
    const int wave = tid >> 6;
    const int l16  = lane & 15;
    const int lhi  = lane >> 4;
    const long p00 = (long)blockIdx.x * 128;
    const int spos = tid >> 3;   // 0..31
    const int sseg = tid & 7;    // 0..7

    // ---- resident W fragments: 24 independent uint4 loads, batch-issued ----
    bf16x8 wf[6][4];
    {
        const unsigned short* wbase = wfb + ((long)(wave * 24) * 64 + lane) * 8;
        #pragma unroll
        for (int j = 0; j < 6; ++j)
            #pragma unroll
            for (int ks = 0; ks < 4; ++ks)
                wf[j][ks] = __builtin_bit_cast(bf16x8,
                    *(const uint4*)(wbase + (j * 4 + ks) * 512));
    }

    // stage a 32-pos tile from 4 float4 regs into xs (cvt + 2 b128 writes)
    auto stage_write = [&](float4 a0, float4 a1, float4 a2, float4 a3) {
        unsigned int t[8] = {
            pk2(a0.x, a0.y), pk2(a0.z, a0.w), pk2(a1.x, a1.y), pk2(a1.z, a1.w),
            pk2(a2.x, a2.y), pk2(a2.z, a2.w), pk2(a3.x, a3.y), pk2(a3.z, a3.w) };
        *(uint4*)(xs + spos * 136 + sseg * 16)     = ((const uint4*)t)[0];
        *(uint4*)(xs + spos * 136 + sseg * 16 + 8) = ((const uint4*)t)[1];
    };

    // MFMA phase: reads xs + resident wf, writes qsm (+bias)
    auto mfma_phase = [&]() {
        f32x4 acc[6][2];
        #pragma unroll
        for (int j = 0; j < 6; ++j)
            #pragma unroll
            for (int nt = 0; nt < 2; ++nt) acc[j][nt] = (f32x4){0.f, 0.f, 0.f, 0.f};

        #pragma unroll
        for (int ks = 0; ks < 4; ++ks) {
            const bf16x8 xf0 = __builtin_bit_cast(bf16x8,
                *(const uint4*)(xs + l16 * 136 + ks * 32 + lhi * 8));
            const bf16x8 xf1 = __builtin_bit_cast(bf16x8,
                *(const uint4*)(xs + (16 + l16) * 136 + ks * 32 + lhi * 8));
            #pragma unroll
            for (int j = 0; j < 6; ++j) {
                acc[j][0] = __builtin_amdgcn_mfma_f32_16x16x32_bf16(wf[j][ks], xf0, acc[j][0], 0, 0, 0);
                acc[j][1] = __builtin_amdgcn_mfma_f32_16x16x32_bf16(wf[j][ks], xf1, acc[j][1], 0, 0, 0);
            }
        }
        #pragma unroll
        for (int j = 0; j < 6; ++j) {
            const float4 bb = *(const float4*)(bqkv + wave * 96 + j * 16 + lhi * 4);
            const int c     = wave * 96 + lhi * 4 + j * 16;
            const int chunk = c >> 3;
            const int sub   = c & 7;          // 0 or 4
            #pragma unroll
            for (int nt = 0; nt < 2; ++nt) {
                const int p = nt * 16 + l16;  // p & 15 == l16
                uint2 u;
                u.x = pk2(acc[j][nt][0] + bb.x, acc[j][nt][1] + bb.y);
                u.y = pk2(acc[j][nt][2] + bb.z, acc[j][nt][3] + bb.w);
                *(uint2*)(qsm + p * 384 + (((chunk ^ l16) << 3) + sub)) = u;
            }
        }
    };

    // epilogue: 256 threads = (p = tid>>3, qh = (tid>>1)&3, h = tid&1)
    auto epilogue = [&](long p0) {
        const int p   = tid >> 3;
        const int qh  = (tid >> 1) & 3;
        const int h   = tid & 1;
        const int psw = p & 15;
        const unsigned short* row = qsm + p * 384;
        const float scale = 0.17677669529663687f;   // 32^-0.5

        float qf[16];
        {
            const int qc = qh * 12 + h * 2;
            #pragma unroll
            for (int cc = 0; cc < 2; ++cc) {
                const uint4 qv = *(const uint4*)(row + (((qc + cc) ^ psw) << 3));
                const unsigned int* w = (const unsigned int*)&qv;
                #pragma unroll
                for (int k = 0; k < 4; ++k) {
                    qf[cc * 8 + 2 * k]     = bf_lo(w[k]);
                    qf[cc * 8 + 2 * k + 1] = bf_hi(w[k]);
                }
            }
        }
        float sc[NHEADS];
        #pragma unroll
        for (int kh = 0; kh < NHEADS; ++kh) {
            float s = 0.f;
            const int kc = kh * 12 + 4 + h * 2;
            #pragma unroll
            for (int cc = 0; cc < 2; ++cc) {
                const uint4 kv = *(const uint4*)(row + (((kc + cc) ^ psw) << 3));
                const unsigned int* w = (const unsigned int*)&kv;
                #pragma unroll
                for (int k = 0; k < 4; ++k) {
                    s = fmaf(bf_lo(w[k]), qf[cc * 8 + 2 * k], s);
                    s = fmaf(bf_hi(w[k]), qf[cc * 8 + 2 * k + 1], s);
                }
            }
            sc[kh] = (s + __shfl_xor(s, 1)) * scale;
        }
        const float m = fmaxf(fmaxf(sc[0], sc[1]), fmaxf(sc[2], sc[3]));
        float ew[NHEADS], sum = 0.f;
        #pragma unroll
        for (int kh = 0; kh < NHEADS; ++kh) { ew[kh] = __expf(sc[kh] - m); sum += ew[kh]; }
        const float inv = 1.f / sum;
        #pragma unroll
        for (int kh = 0; kh < NHEADS; ++kh) ew[kh] *= inv;

        float o[16];
        #pragma unroll
        for (int e = 0; e < 16; ++e) o[e] = 0.f;
        #pragma unroll
        for (int kh = 0; kh < NHEADS; ++kh) {
            const float wk = ew[kh];
            const int vc = kh * 12 + 8 + h * 2;
            #pragma unroll
            for (int cc = 0; cc < 2; ++cc) {
                const uint4 vv = *(const uint4*)(row + (((vc + cc) ^ psw) << 3));
                const unsigned int* w = (const unsigned int*)&vv;
                #pragma unroll
                for (int k = 0; k < 4; ++k) {
                    o[cc * 8 + 2 * k]     = fmaf(wk, bf_lo(w[k]), o[cc * 8 + 2 * k]);
                    o[cc * 8 + 2 * k + 1] = fmaf(wk, bf_hi(w[k]), o[cc * 8 + 2 * k + 1]);
                }
            }
        }
        unsigned int ow[8];
        #pragma unroll
        for (int e = 0; e < 8; ++e) ow[e] = pk2(o[2 * e], o[2 * e + 1]);
        unsigned short* dst = attn_out + (p0 + p) * DMODEL + qh * 32 + h * 16;
        *(uint4*)(dst)     = ((const uint4*)ow)[0];
        *(uint4*)(dst + 8) = ((const uint4*)ow)[1];
    };

    // ---- prologue: stage tile 0 ----
    {
        const float* src = x + (p00 + spos) * DMODEL + sseg * 16;
        stage_write(*(const float4*)(src),     *(const float4*)(src + 4),
                    *(const float4*)(src + 8), *(const float4*)(src + 12));
    }
    __syncthreads();                 // xs(t0) ready

    for (int it = 0; it < 4; ++it) {
        mfma_phase();
        float4 xv0, xv1, xv2, xv3;   // next-tile prefetch (16 VGPR thru epi)
        if (it < 3) {
            const float* src = x + (p00 + (it + 1) * 32 + spos) * DMODEL + sseg * 16;
            xv0 = *(const float4*)(src);      xv1 = *(const float4*)(src + 4);
            xv2 = *(const float4*)(src + 8);  xv3 = *(const float4*)(src + 12);
        }
        __syncthreads();             // qsm ready; xs consumed

        epilogue(p00 + it * 32);
        if (it < 3) {
            stage_write(xv0, xv1, xv2, xv3);   // xs := next tile
            __syncthreads();         // xs ready; qsm free
        }
    }
}

// ---------------------------------------------------------------------------
// Kernel 2: final GEMM partials via bf16 MFMA.
//   C(1024x128) = Aflat(1024x8192 bf16) @ W(8192x128)
// Grid: 32 M-tiles (32 rows) x 16 K-chunks = 512 blocks (2 blocks/CU ->
// stage latency of one block hides under the other's MFMA phase).
// ---------------------------------------------------------------------------
__global__ __launch_bounds__(256, 2) void k_fgemm_mfma(
    const unsigned short* __restrict__ attnBf,   // [1024][8192] bf16 (flat view)
    const unsigned short* __restrict__ WtBf,     // [128][8192] bf16
    float* __restrict__ P)                       // [16][1024][128] f32 partials
{
    __shared__ unsigned short As[32][136];
    __shared__ unsigned short Ws[128][136];

    const int tid   = threadIdx.x;
    const int mtile = blockIdx.x >> 4;     // 0..31
    const int kc    = blockIdx.x & 15;     // 0..15
    const int lane  = tid & 63;
    const int wave  = tid >> 6;
    const int l16   = lane & 15;
    const int lhi   = lane >> 4;

    f32x4 acc[2][2];
    #pragma unroll
    for (int mf = 0; mf < 2; ++mf)
        #pragma unroll
        for (int nt = 0; nt < 2; ++nt) acc[mf][nt] = (f32x4){0.f, 0.f, 0.f, 0.f};

    for (int st = 0; st < 4; ++st) {
        const int k0 = kc * 512 + st * 128;
        __syncthreads();
        // stage A: 32 rows x 128 k = 512 uint4, 2/thread
        #pragma unroll
        for (int i = 0; i < 2; ++i) {
            const int c = tid + i * 256;
            const int m = c >> 4, k8 = c & 15;
            const uint4 v = *(const uint4*)(attnBf + (long)(mtile * 32 + m) * SLEN + k0 + k8 * 8);
            *(uint4*)(&As[m][k8 * 8]) = v;
        }
        // stage W: 128 n-rows x 128 k = 2048 uint4, 8/thread
        #pragma unroll
        for (int i = 0; i < 8; ++i) {
            const int c = tid + i * 256;
            const int n = c >> 4, k8 = c & 15;
            const uint4 v = *(const uint4*)(WtBf + (long)n * SLEN + k0 + k8 * 8);
            *(uint4*)(&Ws[n][k8 * 8]) = v;
        }
        __syncthreads();

        #pragma unroll
        for (int ks = 0; ks < 4; ++ks) {
            const int kk = ks * 32 + lhi * 8;
            bf16x8 af[2], bfr[2];
            #pragma unroll
            for (int mf = 0; mf < 2; ++mf)
                af[mf] = __builtin_bit_cast(bf16x8, *(const uint4*)(&As[mf * 16 + l16][kk]));
            #pragma unroll
            for (int nt = 0; nt < 2; ++nt)
                bfr[nt] = __builtin_bit_cast(bf16x8, *(const uint4*)(&Ws[(wave * 2 + nt) * 16 + l16][kk]));
            #pragma unroll
            for (int mf = 0; mf < 2; ++mf)
                #pragma unroll
                for (int nt = 0; nt < 2; ++nt)
                    acc[mf][nt] = __builtin_amdgcn_mfma_f32_16x16x32_bf16(af[mf], bfr[nt], acc[mf][nt], 0, 0, 0);
        }
    }

    float* Pp = P + ((long)kc * 1024 + mtile * 32) * 128;
    #pragma unroll
    for (int mf = 0; mf < 2; ++mf) {
        #pragma unroll
        for (int nt = 0; nt < 2; ++nt) {
            const int n = (wave * 2 + nt) * 16 + l16;
            #pragma unroll
            for (int r = 0; r < 4; ++r) {
                const int m = mf * 16 + lhi * 4 + r;
                Pp[m * 128 + n] = acc[mf][nt][r];
            }
        }
    }
}

// ---------------------------------------------------------------------------
// Kernel 3: reduce 16 K-chunk partials + bias -> out (also clears poison).
// ---------------------------------------------------------------------------
__global__ __launch_bounds__(256) void k_reduce(
    const float* __restrict__ P, const float* __restrict__ bout,
    float* __restrict__ out)
{
    const int idx = blockIdx.x * 256 + threadIdx.x;
    float v = bout[idx & 127];
    #pragma unroll
    for (int kcc = 0; kcc < 16; ++kcc) v += P[(long)kcc * 131072 + idx];
    out[idx] = v;
}

// ---------------------------------------------------------------------------
extern "C" void kernel_launch(void* const* d_in, const int* in_sizes, int n_in,
                              void* d_out, int out_size, void* d_ws, size_t ws_size,
                              hipStream_t stream)
{
    const float* x    = (const float*)d_in[0];
    const float* Wqkv = (const float*)d_in[1];
    const float* bqkv = (const float*)d_in[2];
    const float* Wout = (const float*)d_in[3];
    const float* bout = (const float*)d_in[4];
    float* out = (float*)d_out;

    // ws: [0,16M) attn bf16 | [16,18M) Wt bf16 | [18,26M) P f32 | [26M..) wfb
    unsigned short* attnBf = (unsigned short*)d_ws;
    unsigned short* WtBf   = (unsigned short*)((char*)d_ws + (16u << 20));
    float*          P      = (float*)((char*)d_ws + (18u << 20));
    unsigned short* wfb    = (unsigned short*)((char*)d_ws + (26u << 20));

    k_prep<<<88, 256, 0, stream>>>(Wout, WtBf, Wqkv, wfb);
    k_qkv_attn_mfma<<<512, 256, 0, stream>>>(x, wfb, bqkv, attnBf);
    k_fgemm_mfma<<<512, 256, 0, stream>>>(attnBf, WtBf, P);
    k_reduce<<<512, 256, 0, stream>>>(P, bout, out);
}

// Round 13
// 38.767 us; speedup vs baseline: 1.7546x; 1.0024x over previous
//
#include <hip/hip_runtime.h>
#include <math.h>

#define NHEADS 4
#define HDIM   32
#define DMODEL 128
#define SLEN   8192
#define BATCH  8
#define QKVC   384   // 3 * NHEADS * HDIM

typedef __bf16 bf16x8 __attribute__((ext_vector_type(8)));
typedef float  f32x4  __attribute__((ext_vector_type(4)));

// round-to-nearest-even f32 -> bf16 bits
static __device__ __forceinline__ unsigned short f2bf(float f) {
    union { float f; unsigned int u; } v; v.f = f;
    unsigned int r = (v.u + 0x7FFFu + ((v.u >> 16) & 1u)) >> 16;
    return (unsigned short)r;
}
// hardware cvt pack (v_cvt_pk_bf16_f32)
static __device__ __forceinline__ unsigned int pk2(float a, float b) {
    unsigned short ua = __builtin_bit_cast(unsigned short, (__bf16)a);
    unsigned short ub = __builtin_bit_cast(unsigned short, (__bf16)b);
    return (unsigned int)ua | ((unsigned int)ub << 16);
}
static __device__ __forceinline__ float bf_lo(unsigned int u) {
    union { unsigned int u; float f; } v; v.u = u << 16; return v.f;
}
static __device__ __forceinline__ float bf_hi(unsigned int u) {
    union { unsigned int u; float f; } v; v.u = u & 0xffff0000u; return v.f;
}

// ---------------------------------------------------------------------------
// Kernel P: prep. blockIdx segments:
//   [0,64) : W_out f32[8192][128] -> Wt bf16 [128][8192] (transpose+cvt)
//   [64,88): W_qkv -> MFMA A-fragment buffer wfb (bf16, fragment order)
// ---------------------------------------------------------------------------
__global__ __launch_bounds__(256) void k_prep(
    const float* __restrict__ Wout, unsigned short* __restrict__ Wt,
    const float* __restrict__ Wqkv, unsigned short* __restrict__ wfb)
{
    const int tid = threadIdx.x;
    const int bx  = blockIdx.x;

    if (bx < 64) {
        __shared__ unsigned short ts[128][136];
        const float* src = Wout + (long)bx * 128 * 128;
        #pragma unroll
        for (int i = 0; i < 64; ++i) {
            const int idx = tid + i * 256;
            const int kk = idx >> 7, n = idx & 127;
            ts[n][kk] = f2bf(src[idx]);
        }
        __syncthreads();
        #pragma unroll
        for (int i = 0; i < 64; ++i) {
            const int idx = tid + i * 256;
            const int n = idx >> 7, kk = idx & 127;
            Wt[(long)n * SLEN + bx * 128 + kk] = ts[n][kk];
        }
    } else {
        const int idx  = (bx - 64) * 256 + tid;   // 0..6143
        const int lane = idx & 63;
        const int ks   = (idx >> 6) & 3;
        const int J    = idx >> 8;                // 0..23 channel tile
        const int ch   = J * 16 + (lane & 15);
        const int kb   = ks * 32 + (lane >> 4) * 8;
        unsigned short t[8];
        #pragma unroll
        for (int e = 0; e < 8; ++e) t[e] = f2bf(Wqkv[(kb + e) * QKVC + ch]);
        *(uint4*)(wfb + (long)idx * 8) = *(const uint4*)t;
    }
}

// ---------------------------------------------------------------------------
// Kernel 1: fused QKV projection + per-position head-mixing attention.
// 512 blocks x 256 thr; FOUR 32-position tiles per block.
// Schedule per tile (2 barriers): issue next-tile loads EARLY (before MFMA,
// covered by MFMA+barrier+epilogue) -> MFMA qkv^T from xs[cur] -> qsm ->
// barrier -> stage_write(xs[cur^1]) + epilogue -> barrier.
// W fragments resident in registers (loaded once, reused 4x).
// ---------------------------------------------------------------------------
__global__ __launch_bounds__(256, 2) void k_qkv_attn_mfma(
    const float* __restrict__ x,
    const unsigned short* __restrict__ wfb,
    const float* __restrict__ bqkv,
    unsigned short* __restrict__ attn_out)   // bf16 [65536][128]
{
    __shared__ unsigned short xs[2][32 * 136];  // double-buffered x tile bf16
    __shared__ unsigned short qsm[32 * 384];    // qkv bf16, chunk-swizzled rows

    const int tid  = threadIdx.x;
    const int lane = tid & 63;
    const int wave = tid >> 6;
    const int l16  = lane & 15;
    const int lhi  = lane >> 4;
    const long p00 = (long)blockIdx.x * 128;
    const int spos = tid >> 3;   // 0..31
    const int sseg = tid & 7;    // 0..7

    // ---- resident W fragments: 24 independent uint4 loads, batch-issued ----
    bf16x8 wf[6][4];
    {
        const unsigned short* wbase = wfb + ((long)(wave * 24) * 64 + lane) * 8;
        #pragma unroll
        for (int j = 0; j < 6; ++j)
            #pragma unroll
            for (int ks = 0; ks < 4; ++ks)
                wf[j][ks] = __builtin_bit_cast(bf16x8,
                    *(const uint4*)(wbase + (j * 4 + ks) * 512));
    }

    // stage a 32-pos tile from 4 float4 regs into xs[buf]
    auto stage_write = [&](int buf, float4 a0, float4 a1, float4 a2, float4 a3) {
        unsigned int t[8] = {
            pk2(a0.x, a0.y), pk2(a0.z, a0.w), pk2(a1.x, a1.y), pk2(a1.z, a1.w),
            pk2(a2.x, a2.y), pk2(a2.z, a2.w), pk2(a3.x, a3.y), pk2(a3.z, a3.w) };
        *(uint4*)(xs[buf] + spos * 136 + sseg * 16)     = ((const uint4*)t)[0];
        *(uint4*)(xs[buf] + spos * 136 + sseg * 16 + 8) = ((const uint4*)t)[1];
    };

    // MFMA phase: reads xs[buf] + resident wf, writes qsm (+bias)
    auto mfma_phase = [&](int buf) {
        f32x4 acc[6][2];
        #pragma unroll
        for (int j = 0; j < 6; ++j)
            #pragma unroll
            for (int nt = 0; nt < 2; ++nt) acc[j][nt] = (f32x4){0.f, 0.f, 0.f, 0.f};

        #pragma unroll
        for (int ks = 0; ks < 4; ++ks) {
            const bf16x8 xf0 = __builtin_bit_cast(bf16x8,
                *(const uint4*)(xs[buf] + l16 * 136 + ks * 32 + lhi * 8));
            const bf16x8 xf1 = __builtin_bit_cast(bf16x8,
                *(const uint4*)(xs[buf] + (16 + l16) * 136 + ks * 32 + lhi * 8));
            #pragma unroll
            for (int j = 0; j < 6; ++j) {
                acc[j][0] = __builtin_amdgcn_mfma_f32_16x16x32_bf16(wf[j][ks], xf0, acc[j][0], 0, 0, 0);
                acc[j][1] = __builtin_amdgcn_mfma_f32_16x16x32_bf16(wf[j][ks], xf1, acc[j][1], 0, 0, 0);
            }
        }
        #pragma unroll
        for (int j = 0; j < 6; ++j) {
            const float4 bb = *(const float4*)(bqkv + wave * 96 + j * 16 + lhi * 4);
            const int c     = wave * 96 + lhi * 4 + j * 16;
            const int chunk = c >> 3;
            const int sub   = c & 7;          // 0 or 4
            #pragma unroll
            for (int nt = 0; nt < 2; ++nt) {
                const int p = nt * 16 + l16;  // p & 15 == l16
                uint2 u;
                u.x = pk2(acc[j][nt][0] + bb.x, acc[j][nt][1] + bb.y);
                u.y = pk2(acc[j][nt][2] + bb.z, acc[j][nt][3] + bb.w);
                *(uint2*)(qsm + p * 384 + (((chunk ^ l16) << 3) + sub)) = u;
            }
        }
    };

    // epilogue: 256 threads = (p = tid>>3, qh = (tid>>1)&3, h = tid&1)
    auto epilogue = [&](long p0) {
        const int p   = tid >> 3;
        const int qh  = (tid >> 1) & 3;
        const int h   = tid & 1;
        const int psw = p & 15;
        const unsigned short* row = qsm + p * 384;
        const float scale = 0.17677669529663687f;   // 32^-0.5

        float qf[16];
        {
            const int qc = qh * 12 + h * 2;
            #pragma unroll
            for (int cc = 0; cc < 2; ++cc) {
                const uint4 qv = *(const uint4*)(row + (((qc + cc) ^ psw) << 3));
                const unsigned int* w = (const unsigned int*)&qv;
                #pragma unroll
                for (int k = 0; k < 4; ++k) {
                    qf[cc * 8 + 2 * k]     = bf_lo(w[k]);
                    qf[cc * 8 + 2 * k + 1] = bf_hi(w[k]);
                }
            }
        }
        float sc[NHEADS];
        #pragma unroll
        for (int kh = 0; kh < NHEADS; ++kh) {
            float s = 0.f;
            const int kc = kh * 12 + 4 + h * 2;
            #pragma unroll
            for (int cc = 0; cc < 2; ++cc) {
                const uint4 kv = *(const uint4*)(row + (((kc + cc) ^ psw) << 3));
                const unsigned int* w = (const unsigned int*)&kv;
                #pragma unroll
                for (int k = 0; k < 4; ++k) {
                    s = fmaf(bf_lo(w[k]), qf[cc * 8 + 2 * k], s);
                    s = fmaf(bf_hi(w[k]), qf[cc * 8 + 2 * k + 1], s);
                }
            }
            sc[kh] = (s + __shfl_xor(s, 1)) * scale;
        }
        const float m = fmaxf(fmaxf(sc[0], sc[1]), fmaxf(sc[2], sc[3]));
        float ew[NHEADS], sum = 0.f;
        #pragma unroll
        for (int kh = 0; kh < NHEADS; ++kh) { ew[kh] = __expf(sc[kh] - m); sum += ew[kh]; }
        const float inv = 1.f / sum;
        #pragma unroll
        for (int kh = 0; kh < NHEADS; ++kh) ew[kh] *= inv;

        float o[16];
        #pragma unroll
        for (int e = 0; e < 16; ++e) o[e] = 0.f;
        #pragma unroll
        for (int kh = 0; kh < NHEADS; ++kh) {
            const float wk = ew[kh];
            const int vc = kh * 12 + 8 + h * 2;
            #pragma unroll
            for (int cc = 0; cc < 2; ++cc) {
                const uint4 vv = *(const uint4*)(row + (((vc + cc) ^ psw) << 3));
                const unsigned int* w = (const unsigned int*)&vv;
                #pragma unroll
                for (int k = 0; k < 4; ++k) {
                    o[cc * 8 + 2 * k]     = fmaf(wk, bf_lo(w[k]), o[cc * 8 + 2 * k]);
                    o[cc * 8 + 2 * k + 1] = fmaf(wk, bf_hi(w[k]), o[cc * 8 + 2 * k + 1]);
                }
            }
        }
        unsigned int ow[8];
        #pragma unroll
        for (int e = 0; e < 8; ++e) ow[e] = pk2(o[2 * e], o[2 * e + 1]);
        unsigned short* dst = attn_out + (p0 + p) * DMODEL + qh * 32 + h * 16;
        *(uint4*)(dst)     = ((const uint4*)ow)[0];
        *(uint4*)(dst + 8) = ((const uint4*)ow)[1];
    };

    // ---- prologue: stage tile 0 into xs[0] ----
    {
        const float* src = x + (p00 + spos) * DMODEL + sseg * 16;
        stage_write(0, *(const float4*)(src),     *(const float4*)(src + 4),
                       *(const float4*)(src + 8), *(const float4*)(src + 12));
    }
    __syncthreads();                 // xs[0] ready

    for (int it = 0; it < 4; ++it) {
        const int cur = it & 1;

        // issue next-tile loads EARLY: covered by MFMA + barrier + epilogue
        float4 xv0, xv1, xv2, xv3;
        if (it < 3) {
            const float* src = x + (p00 + (it + 1) * 32 + spos) * DMODEL + sseg * 16;
            xv0 = *(const float4*)(src);      xv1 = *(const float4*)(src + 4);
            xv2 = *(const float4*)(src + 8);  xv3 = *(const float4*)(src + 12);
        }

        mfma_phase(cur);
        __syncthreads();             // qsm ready; xs[cur] consumed

        if (it < 3)
            stage_write(cur ^ 1, xv0, xv1, xv2, xv3);   // idle buffer, no race
        epilogue(p00 + it * 32);
        __syncthreads();             // qsm free; xs[cur^1] ready
    }
}

// ---------------------------------------------------------------------------
// Kernel 2: final GEMM partials via bf16 MFMA.
//   C(1024x128) = Aflat(1024x8192 bf16) @ W(8192x128)
// Grid: 32 M-tiles (32 rows) x 16 K-chunks = 512 blocks (2 blocks/CU).
// ---------------------------------------------------------------------------
__global__ __launch_bounds__(256, 2) void k_fgemm_mfma(
    const unsigned short* __restrict__ attnBf,   // [1024][8192] bf16 (flat view)
    const unsigned short* __restrict__ WtBf,     // [128][8192] bf16
    float* __restrict__ P)                       // [16][1024][128] f32 partials
{
    __shared__ unsigned short As[32][136];
    __shared__ unsigned short Ws[128][136];

    const int tid   = threadIdx.x;
    const int mtile = blockIdx.x >> 4;     // 0..31
    const int kc    = blockIdx.x & 15;     // 0..15
    const int lane  = tid & 63;
    const int wave  = tid >> 6;
    const int l16   = lane & 15;
    const int lhi   = lane >> 4;

    f32x4 acc[2][2];
    #pragma unroll
    for (int mf = 0; mf < 2; ++mf)
        #pragma unroll
        for (int nt = 0; nt < 2; ++nt) acc[mf][nt] = (f32x4){0.f, 0.f, 0.f, 0.f};

    for (int st = 0; st < 4; ++st) {
        const int k0 = kc * 512 + st * 128;
        __syncthreads();
        #pragma unroll
        for (int i = 0; i < 2; ++i) {
            const int c = tid + i * 256;
            const int m = c >> 4, k8 = c & 15;
            const uint4 v = *(const uint4*)(attnBf + (long)(mtile * 32 + m) * SLEN + k0 + k8 * 8);
            *(uint4*)(&As[m][k8 * 8]) = v;
        }
        #pragma unroll
        for (int i = 0; i < 8; ++i) {
            const int c = tid + i * 256;
            const int n = c >> 4, k8 = c & 15;
            const uint4 v = *(const uint4*)(WtBf + (long)n * SLEN + k0 + k8 * 8);
            *(uint4*)(&Ws[n][k8 * 8]) = v;
        }
        __syncthreads();

        #pragma unroll
        for (int ks = 0; ks < 4; ++ks) {
            const int kk = ks * 32 + lhi * 8;
            bf16x8 af[2], bfr[2];
            #pragma unroll
            for (int mf = 0; mf < 2; ++mf)
                af[mf] = __builtin_bit_cast(bf16x8, *(const uint4*)(&As[mf * 16 + l16][kk]));
            #pragma unroll
            for (int nt = 0; nt < 2; ++nt)
                bfr[nt] = __builtin_bit_cast(bf16x8, *(const uint4*)(&Ws[(wave * 2 + nt) * 16 + l16][kk]));
            #pragma unroll
            for (int mf = 0; mf < 2; ++mf)
                #pragma unroll
                for (int nt = 0; nt < 2; ++nt)
                    acc[mf][nt] = __builtin_amdgcn_mfma_f32_16x16x32_bf16(af[mf], bfr[nt], acc[mf][nt], 0, 0, 0);
        }
    }

    float* Pp = P + ((long)kc * 1024 + mtile * 32) * 128;
    #pragma unroll
    for (int mf = 0; mf < 2; ++mf) {
        #pragma unroll
        for (int nt = 0; nt < 2; ++nt) {
            const int n = (wave * 2 + nt) * 16 + l16;
            #pragma unroll
            for (int r = 0; r < 4; ++r) {
                const int m = mf * 16 + lhi * 4 + r;
                Pp[m * 128 + n] = acc[mf][nt][r];
            }
        }
    }
}

// ---------------------------------------------------------------------------
// Kernel 3: reduce 16 K-chunk partials + bias -> out (also clears poison).
// ---------------------------------------------------------------------------
__global__ __launch_bounds__(256) void k_reduce(
    const float* __restrict__ P, const float* __restrict__ bout,
    float* __restrict__ out)
{
    const int idx = blockIdx.x * 256 + threadIdx.x;
    float v = bout[idx & 127];
    #pragma unroll
    for (int kcc = 0; kcc < 16; ++kcc) v += P[(long)kcc * 131072 + idx];
    out[idx] = v;
}

// ---------------------------------------------------------------------------
extern "C" void kernel_launch(void* const* d_in, const int* in_sizes, int n_in,
                              void* d_out, int out_size, void* d_ws, size_t ws_size,
                              hipStream_t stream)
{
    const float* x    = (const float*)d_in[0];
    const float* Wqkv = (const float*)d_in[1];
    const float* bqkv = (const float*)d_in[2];
    const float* Wout = (const float*)d_in[3];
    const float* bout = (const float*)d_in[4];
    float* out = (float*)d_out;

    // ws: [0,16M) attn bf16 | [16,18M) Wt bf16 | [18,26M) P f32 | [26M..) wfb
    unsigned short* attnBf = (unsigned short*)d_ws;
    unsigned short* WtBf   = (unsigned short*)((char*)d_ws + (16u << 20));
    float*          P      = (float*)((char*)d_ws + (18u << 20));
    unsigned short* wfb    = (unsigned short*)((char*)d_ws + (26u << 20));

    k_prep<<<88, 256, 0, stream>>>(Wout, WtBf, Wqkv, wfb);
    k_qkv_attn_mfma<<<512, 256, 0, stream>>>(x, wfb, bqkv, attnBf);
    k_fgemm_mfma<<<512, 256, 0, stream>>>(attnBf, WtBf, P);
    k_reduce<<<512, 256, 0, stream>>>(P, bout, out);
}